// Round 1
// 1152.566 us; speedup vs baseline: 1.0519x; 1.0519x over previous
//
#include <hip/hip_runtime.h>
#include <hip/hip_bf16.h>

#define NN 50000
#define NE 800000
#define DIMX 288
#define NPB 16   // nodes per block in k_linear1 / k_gate

typedef float float4v __attribute__((ext_vector_type(4)));
typedef short short8 __attribute__((ext_vector_type(8)));

__device__ __forceinline__ float b2f(unsigned short u) {
  return __uint_as_float(((unsigned int)u) << 16);
}
__device__ __forceinline__ unsigned short f2b(float f) {
  unsigned int x = __float_as_uint(f);
  x += 0x7fffu + ((x >> 16) & 1u);
  return (unsigned short)(x >> 16);
}
__device__ __forceinline__ float ldf(const void* p, long i, int f32) {
  return f32 ? ((const float*)p)[i] : b2f(((const unsigned short*)p)[i]);
}
__device__ __forceinline__ int ldidx(const int* p, long i, int i64) {
  return i64 ? p[2 * i] : p[i];
}

// ---------------- Kernel 0: dtype detector ----------------
__global__ void k_detect(const unsigned short* __restrict__ pos_u16,
                         const int* __restrict__ eidx_i32,
                         int* __restrict__ flags) {
  if (threadIdx.x == 0 && blockIdx.x == 0) {
    int insane = 0;
    for (int i = 0; i < 128; ++i) {
      unsigned short u = pos_u16[i];
      int e = (u >> 7) & 0xff;
      if (e >= 0xC2) insane++;          // |x| >= 2^67 impossible for bf16 pos in [0,10]
    }
    flags[0] = (insane >= 2) ? 1 : 0;
    int nz = 0;
    for (int i = 1; i < 16; i += 2) nz += (eidx_i32[i] != 0);
    flags[1] = (nz == 0) ? 1 : 0;       // int64 high words all zero
  }
}

// ---------------- Counting sort by dst: zero-cnt, hist, scan, scatter ----------------
__global__ __launch_bounds__(256) void k_zero_cnt(int* __restrict__ cnt) {
  int i = blockIdx.x * 256 + threadIdx.x;
  if (i < NN) cnt[i] = 0;
}

__global__ __launch_bounds__(256) void k_hist(const int* __restrict__ eidx,
                                              int* __restrict__ cnt,
                                              const int* __restrict__ flags) {
  const int i64 = flags[1];
  long e = (long)blockIdx.x * 256 + threadIdx.x;
  if (e < NE) {
    int d = ldidx(eidx, NE + e, i64);
    atomicAdd(&cnt[d], 1);
  }
}

// single block, 1024 threads: exclusive prefix sum of cnt -> cursor
__global__ __launch_bounds__(1024) void k_scan(const int* __restrict__ cnt,
                                               int* __restrict__ cursor) {
  __shared__ int part[1024];
  int t = threadIdx.x;
  const int CH = (NN + 1023) / 1024;   // 49
  int lo = t * CH, hi = lo + CH; if (hi > NN) hi = NN;
  int s = 0;
  for (int i = lo; i < hi; ++i) s += cnt[i];
  part[t] = s;
  __syncthreads();
  for (int off = 1; off < 1024; off <<= 1) {
    int v = (t >= off) ? part[t - off] : 0;
    __syncthreads();
    part[t] += v;
    __syncthreads();
  }
  int run = (t > 0) ? part[t - 1] : 0;
  for (int i = lo; i < hi; ++i) { int c = cnt[i]; cursor[i] = run; run += c; }
}

__global__ __launch_bounds__(256) void k_scatter(const int* __restrict__ eidx,
                                                 int* __restrict__ cursor,
                                                 unsigned long long* __restrict__ sedge,
                                                 const int* __restrict__ flags) {
  const int i64 = flags[1];
  long e = (long)blockIdx.x * 256 + threadIdx.x;
  if (e < NE) {
    int s = ldidx(eidx, e, i64);
    int d = ldidx(eidx, NE + e, i64);
    int p = atomicAdd(&cursor[d], 1);
    sedge[p] = ((unsigned long long)(unsigned)d << 32) | (unsigned)s;
  }
}

// ---------------- Kernel 1: si1 = irreps_linear(nodes) -> bf16 ----------------
// 16 nodes/block (4 per wave) to amortize weight staging.
__global__ __launch_bounds__(256) void k_linear1(
    const void* __restrict__ nodes,
    const void* __restrict__ W0,
    const void* __restrict__ W1,
    const void* __restrict__ W2,
    unsigned short* __restrict__ si1,
    const int* __restrict__ flags) {
  const int f32 = flags[0];
  __shared__ float Ws[3072];
  __shared__ float xs[NPB * DIMX];
  int tid = threadIdx.x;
  for (int idx = tid; idx < 3072; idx += 256) {
    int l = idx >> 10, rem = idx & 1023;
    const void* w = (l == 0) ? W0 : ((l == 1) ? W1 : W2);
    Ws[idx] = ldf(w, rem, f32);
  }
  long base = (long)blockIdx.x * NPB;
  for (int idx = tid; idx < NPB * DIMX; idx += 256)
    xs[idx] = ldf(nodes, base * DIMX + idx, f32);
  __syncthreads();
  int wid = tid >> 6, lane = tid & 63;
  #pragma unroll 1
  for (int t = 0; t < 4; ++t) {
    int nl = wid * 4 + t;
    long node = base + nl;
    const float* x = xs + nl * DIMX;
    #pragma unroll
    for (int r = 0; r < 5; ++r) {
      int j = r * 64 + lane;
      if (j < DIMX) {
        float acc = 0.f;
        if (j < 32) {
          #pragma unroll
          for (int i = 0; i < 32; ++i) acc += x[i] * Ws[i * 32 + j];
        } else if (j < 128) {
          unsigned jj = j - 32; int m = jj / 3u, c = jj % 3u;
          #pragma unroll
          for (int i = 0; i < 32; ++i) acc += x[32 + 3 * i + c] * Ws[1024 + i * 32 + m];
        } else {
          unsigned jj = j - 128; int m = jj / 5u, c = jj % 5u;
          #pragma unroll
          for (int i = 0; i < 32; ++i) acc += x[128 + 5 * i + c] * Ws[2048 + i * 32 + m];
        }
        si1[node * DIMX + j] = f2b(acc);
      }
    }
  }
}

// ---------------- Kernel 2: zero the conv accumulator ----------------
__global__ __launch_bounds__(256) void k_zero(float* __restrict__ conv) {
  long idx = (long)blockIdx.x * 256 + threadIdx.x;
  if (idx < (long)NN * DIMX / 4) {
    float4 z; z.x = 0.f; z.y = 0.f; z.z = 0.f; z.w = 0.f;
    ((float4*)conv)[idx] = z;
  }
}

// ---------------- Kernel 3: fused edge kernel (consumes dst-sorted edges) ----------------
// Phase A: stage Wr2^T in ov; geometry; h (0.25 folded) -> A-frags; 28 MFMA.
// Barrier. Phase B: ov reused as per-wave bf16 row cache; each wave batch-
// gathers its 16 source rows (8 loads in flight), then per edge: unload w
// from C-regs to wev, compute messages from LDS, and ACCUMULATE in VGPRs
// across the run of equal dst (edges are sorted by dst); flush via atomicAdd
// only at dst changes + once at the end (~8x fewer atomics than per-edge).
__global__ __launch_bounds__(256) void k_edges(
    const void* __restrict__ pos,
    const unsigned long long* __restrict__ sedge,
    const void* __restrict__ Wr1,
    const void* __restrict__ br1,
    const void* __restrict__ Wr2,
    const unsigned short* __restrict__ si1,
    float* __restrict__ conv,
    const int* __restrict__ flags) {
  const int f32 = flags[0];
  __shared__ unsigned short ov[18944];  // phase A: wr2t[j*72+k] (16128); phase B: xrows[row*296+i] (18944)
  __shared__ float wr1s[576];           // Wr1 [8][64] + br1 [64]
  __shared__ float geom[64][16];        // Y1(3) Y2(5) rbf(8)
  __shared__ unsigned int sdv[2][64];   // src, dst
  __shared__ float wev[4][228];         // per-wave current-edge w (norm folded)
  int tid = threadIdx.x, lane = tid & 63, wid = tid >> 6;

  for (int idx = tid; idx < 512; idx += 256) wr1s[idx] = ldf(Wr1, idx, f32);
  if (tid < 64) wr1s[512 + tid] = ldf(br1, tid, f32);
  for (int idx = tid; idx < 64 * 224; idx += 256) {   // global-coalesced, transpose into LDS
    int k = idx / 224, j = idx - k * 224;
    ov[j * 72 + k] = f2b(ldf(Wr2, idx, f32));
  }
  if (tid < 64) {
    long e = (long)blockIdx.x * 64 + tid;
    unsigned long long pr = sedge[e];
    int s = (int)(pr & 0xffffffffu);
    int d = (int)(pr >> 32);
    sdv[0][tid] = (unsigned)s; sdv[1][tid] = (unsigned)d;
    float rx = ldf(pos, 3 * (long)s, f32)     - ldf(pos, 3 * (long)d, f32);
    float ry = ldf(pos, 3 * (long)s + 1, f32) - ldf(pos, 3 * (long)d + 1, f32);
    float rz = ldf(pos, 3 * (long)s + 2, f32) - ldf(pos, 3 * (long)d + 2, f32);
    float dd = sqrtf(rx * rx + ry * ry + rz * rz + 1e-12f);
    float inv = 1.0f / dd;
    float ux = rx * inv, uy = ry * inv, uz = rz * inv;
    geom[tid][0] = ux; geom[tid][1] = uy; geom[tid][2] = uz;
    geom[tid][3] = ux * uy;
    geom[tid][4] = uy * uz;
    geom[tid][5] = (3.f * uz * uz - 1.f) * 0.28867513459481287f;
    geom[tid][6] = ux * uz;
    geom[tid][7] = (ux * ux - uy * uy) * 0.5f;
    #pragma unroll
    for (int k = 0; k < 8; ++k) {
      float t = dd - (float)k * (5.0f / 7.0f);
      geom[tid][8 + k] = __expf(-t * t);
    }
  }
  __syncthreads();

  const int q = lane >> 4, colA = lane & 15;
  const int myrow0 = wid * 16;

  // --- h (scaled by 0.25 = 1/sqrt(AVG_DEG), exact pow2) into A-fragments ---
  short8 afrag0, afrag1;
  {
    const float* rb = &geom[myrow0 + colA][8];
    #pragma unroll
    for (int i = 0; i < 8; ++i) {
      int k = q * 8 + i;
      float a = wr1s[512 + k];
      #pragma unroll
      for (int r = 0; r < 8; ++r) a += rb[r] * wr1s[r * 64 + k];
      afrag0[i] = (short)f2b(0.25f * a / (1.f + __expf(-a)));
      int k2 = 32 + q * 8 + i;
      float a2 = wr1s[512 + k2];
      #pragma unroll
      for (int r = 0; r < 8; ++r) a2 += rb[r] * wr1s[r * 64 + k2];
      afrag1[i] = (short)f2b(0.25f * a2 / (1.f + __expf(-a2)));
    }
  }

  // --- 28 MFMA: w for all 16 edges of this wave ---
  float4v acc[14];
  #pragma unroll
  for (int t = 0; t < 14; ++t) {
    int j = t * 16 + colA;
    short8 b0 = *(const short8*)&ov[j * 72 + q * 8];
    short8 b1 = *(const short8*)&ov[j * 72 + 32 + q * 8];
    float4v c = {0.f, 0.f, 0.f, 0.f};
    c = __builtin_amdgcn_mfma_f32_16x16x32_bf16(afrag0, b0, c, 0, 0, 0);
    c = __builtin_amdgcn_mfma_f32_16x16x32_bf16(afrag1, b1, c, 0, 0, 0);
    acc[t] = c;
  }

  __syncthreads();   // all waves done reading wr2t; ov becomes row cache

  // --- batch-gather this wave's 16 source rows (bf16, raw copy, b128 I/O) ---
  if (lane < 36) {
    #pragma unroll
    for (int b = 0; b < 2; ++b) {
      uint4 t[8];
      #pragma unroll
      for (int e = 0; e < 8; ++e) {
        unsigned s = sdv[0][myrow0 + b * 8 + e];
        t[e] = ((const uint4*)(si1 + (size_t)s * DIMX))[lane];
      }
      #pragma unroll
      for (int e = 0; e < 8; ++e) {
        ((uint4*)&ov[(size_t)(myrow0 + b * 8 + e) * 296])[lane] = t[e];
      }
    }
  }
  asm volatile("" ::: "memory");

  // --- per-lane output accumulators for the current dst run ---
  float accv[5] = {0.f, 0.f, 0.f, 0.f, 0.f};
  unsigned cur_d = sdv[1][myrow0];

  #pragma unroll 1
  for (int g = 0; g < 4; ++g) {
    #pragma unroll
    for (int reg = 0; reg < 4; ++reg) {
      const int el = g * 4 + reg;
      const int eb = myrow0 + el;
      if (q == g) {
        #pragma unroll
        for (int t = 0; t < 14; ++t) wev[wid][t * 16 + colA] = acc[t][reg];
      }
      asm volatile("" ::: "memory");
      {
        unsigned dn = sdv[1][eb];
        if (dn != cur_d) {           // wave-uniform: flush the finished run
          float* cv = conv + (size_t)cur_d * DIMX;
          #pragma unroll
          for (int r = 0; r < 5; ++r) {
            int j = r * 64 + lane;
            if (j < DIMX) { atomicAdd(cv + j, accv[r]); accv[r] = 0.f; }
          }
          cur_d = dn;
        }
        const float* G = geom[eb];
        float y1x = G[0], y1y = G[1], y1z = G[2];
        float y20 = G[3], y21 = G[4], y22 = G[5], y23 = G[6], y24 = G[7];
        const unsigned short* X = &ov[(size_t)eb * 296];
        const float* W = wev[wid];
        #pragma unroll
        for (int r = 0; r < 5; ++r) {
          int j = r * 64 + lane;
          if (j < DIMX) {
            float val;
            if (j < 32) {
              int m = j;
              float d1 = b2f(X[32 + 3 * m]) * y1x + b2f(X[33 + 3 * m]) * y1y + b2f(X[34 + 3 * m]) * y1z;
              float d2 = b2f(X[128 + 5 * m]) * y20 + b2f(X[129 + 5 * m]) * y21 + b2f(X[130 + 5 * m]) * y22
                       + b2f(X[131 + 5 * m]) * y23 + b2f(X[132 + 5 * m]) * y24;
              val = W[m] * b2f(X[m]) + W[128 + m] * d1 + W[192 + m] * d2;
            } else if (j < 128) {
              unsigned jj = j - 32; int m = jj / 3u, c = jj % 3u;
              float Yc = (c == 0) ? y1x : ((c == 1) ? y1y : y1z);
              val = W[32 + m] * b2f(X[j]) + W[96 + m] * b2f(X[m]) * Yc;
            } else {
              unsigned jj = j - 128; int m = jj / 5u, c = jj % 5u;
              float Yc = (c == 0) ? y20 : (c == 1) ? y21 : (c == 2) ? y22 : (c == 3) ? y23 : y24;
              val = W[64 + m] * b2f(X[j]) + W[160 + m] * b2f(X[m]) * Yc;
            }
            accv[r] += val;
          }
        }
      }
      asm volatile("" ::: "memory");
    }
  }
  // final flush for the last run
  {
    float* cv = conv + (size_t)cur_d * DIMX;
    #pragma unroll
    for (int r = 0; r < 5; ++r) {
      int j = r * 64 + lane;
      if (j < DIMX) atomicAdd(cv + j, accv[r]);
    }
  }
}

// ---------------- Kernel 4: si2 = linear(conv); mixed = nodes + si2; gate -> fp32 ----------------
// 16 nodes/block; gate state is per-node & same-wave -> no block barriers in loop.
__global__ __launch_bounds__(256) void k_gate(
    const float* __restrict__ conv,
    const void* __restrict__ nodes,
    const void* __restrict__ W0,
    const void* __restrict__ W1,
    const void* __restrict__ W2,
    const void* __restrict__ Wg,
    float* __restrict__ out,
    const int* __restrict__ flags) {
  const int f32 = flags[0];
  __shared__ float Ws[3072];
  __shared__ float Wgs[2048];
  __shared__ float xs[NPB * DIMX];
  __shared__ float m0s[NPB][33];
  __shared__ float gs[NPB][65];
  int tid = threadIdx.x;
  for (int idx = tid; idx < 3072; idx += 256) {
    int l = idx >> 10, rem = idx & 1023;
    const void* w = (l == 0) ? W0 : ((l == 1) ? W1 : W2);
    Ws[idx] = ldf(w, rem, f32);
  }
  for (int idx = tid; idx < 2048; idx += 256) Wgs[idx] = ldf(Wg, idx, f32);
  long base = (long)blockIdx.x * NPB;
  for (int idx = tid; idx < NPB * DIMX; idx += 256) xs[idx] = conv[base * DIMX + idx];
  __syncthreads();
  int wid = tid >> 6, lane = tid & 63;
  #pragma unroll 1
  for (int t = 0; t < 4; ++t) {
    int nl = wid * 4 + t;
    long node = base + nl;
    const float* x = xs + nl * DIMX;
    float mixed[5];
    #pragma unroll
    for (int r = 0; r < 5; ++r) {
      int j = r * 64 + lane;
      if (j < DIMX) {
        float acc = 0.f;
        if (j < 32) {
          #pragma unroll
          for (int i = 0; i < 32; ++i) acc += x[i] * Ws[i * 32 + j];
        } else if (j < 128) {
          unsigned jj = j - 32; int m = jj / 3u, c = jj % 3u;
          #pragma unroll
          for (int i = 0; i < 32; ++i) acc += x[32 + 3 * i + c] * Ws[1024 + i * 32 + m];
        } else {
          unsigned jj = j - 128; int m = jj / 5u, c = jj % 5u;
          #pragma unroll
          for (int i = 0; i < 32; ++i) acc += x[128 + 5 * i + c] * Ws[2048 + i * 32 + m];
        }
        acc += ldf(nodes, node * DIMX + j, f32);
        mixed[r] = acc;
        if (j < 32) m0s[nl][j] = acc;
      }
    }
    asm volatile("" ::: "memory");
    {
      float ga = 0.f;
      #pragma unroll
      for (int m = 0; m < 32; ++m) ga += m0s[nl][m] * Wgs[m * 64 + lane];
      gs[nl][lane] = 1.f / (1.f + __expf(-ga));
    }
    asm volatile("" ::: "memory");
    #pragma unroll
    for (int r = 0; r < 5; ++r) {
      int j = r * 64 + lane;
      if (j < DIMX) {
        float v = mixed[r];
        float o;
        if (j < 32) {
          o = v / (1.f + __expf(-v));
        } else if (j < 128) {
          int m = (unsigned)(j - 32) / 3u; o = v * gs[nl][m];
        } else {
          int m = (unsigned)(j - 128) / 5u; o = v * gs[nl][32 + m];
        }
        out[node * DIMX + j] = o;
      }
    }
  }
}

extern "C" void kernel_launch(void* const* d_in, const int* in_sizes, int n_in,
                              void* d_out, int out_size, void* d_ws, size_t ws_size,
                              hipStream_t stream) {
  const void* nodes = d_in[0];
  const void* pos   = d_in[1];
  const void* W0    = d_in[2];
  const void* W1    = d_in[3];
  const void* W2    = d_in[4];
  const void* Wr1   = d_in[5];
  const void* br1   = d_in[6];
  const void* Wr2   = d_in[7];
  const void* Wg    = d_in[8];
  const int* eidx   = (const int*)d_in[10];

  // workspace layout
  int* flags = (int*)d_ws;
  unsigned short* si1 = (unsigned short*)((char*)d_ws + 256);
  size_t conv_off = 256 + (size_t)NN * DIMX * 2;                 // 28,800,256
  float* conv = (float*)((char*)d_ws + conv_off);
  size_t cnt_off = conv_off + (size_t)NN * DIMX * 4;             // 86,400,256
  int* cnt    = (int*)((char*)d_ws + cnt_off);
  int* cursor = (int*)((char*)d_ws + cnt_off + (size_t)NN * 4);  // 86,600,256
  unsigned long long* sedge =
      (unsigned long long*)((char*)d_ws + cnt_off + 2 * (size_t)NN * 4);  // 86,800,256
  float* out = (float*)d_out;

  hipLaunchKernelGGL(k_detect, dim3(1), dim3(64), 0, stream,
                     (const unsigned short*)pos, eidx, flags);
  // counting sort of edges by dst
  hipLaunchKernelGGL(k_zero_cnt, dim3((NN + 255) / 256), dim3(256), 0, stream, cnt);
  hipLaunchKernelGGL(k_hist, dim3((NE + 255) / 256), dim3(256), 0, stream, eidx, cnt, flags);
  hipLaunchKernelGGL(k_scan, dim3(1), dim3(1024), 0, stream, cnt, cursor);
  hipLaunchKernelGGL(k_scatter, dim3((NE + 255) / 256), dim3(256), 0, stream,
                     eidx, cursor, sedge, flags);
  // node pipeline
  hipLaunchKernelGGL(k_linear1, dim3(NN / NPB), dim3(256), 0, stream,
                     nodes, W0, W1, W2, si1, flags);
  hipLaunchKernelGGL(k_zero, dim3((NN * DIMX / 4 + 255) / 256), dim3(256), 0, stream, conv);
  hipLaunchKernelGGL(k_edges, dim3(NE / 64), dim3(256), 0, stream,
                     pos, sedge, Wr1, br1, Wr2, si1, conv, flags);
  hipLaunchKernelGGL(k_gate, dim3(NN / NPB), dim3(256), 0, stream,
                     conv, nodes, W0, W1, W2, Wg, out, flags);
}

// Round 2
// 1141.903 us; speedup vs baseline: 1.0617x; 1.0093x over previous
//
#include <hip/hip_runtime.h>
#include <hip/hip_bf16.h>

#define NN 50000
#define NE 800000
#define DIMX 288
#define NPB 16   // nodes per block in k_linear1 / k_gate

typedef float float4v __attribute__((ext_vector_type(4)));
typedef short short8 __attribute__((ext_vector_type(8)));

__device__ __forceinline__ float b2f(unsigned short u) {
  return __uint_as_float(((unsigned int)u) << 16);
}
__device__ __forceinline__ unsigned short f2b(float f) {
  unsigned int x = __float_as_uint(f);
  x += 0x7fffu + ((x >> 16) & 1u);
  return (unsigned short)(x >> 16);
}
__device__ __forceinline__ float ldf(const void* p, long i, int f32) {
  return f32 ? ((const float*)p)[i] : b2f(((const unsigned short*)p)[i]);
}
__device__ __forceinline__ int ldidx(const int* p, long i, int i64) {
  return i64 ? p[2 * i] : p[i];
}

// ---------------- Kernel 0: dtype detector ----------------
__global__ void k_detect(const unsigned short* __restrict__ pos_u16,
                         const int* __restrict__ eidx_i32,
                         int* __restrict__ flags) {
  if (threadIdx.x == 0 && blockIdx.x == 0) {
    int insane = 0;
    for (int i = 0; i < 128; ++i) {
      unsigned short u = pos_u16[i];
      int e = (u >> 7) & 0xff;
      if (e >= 0xC2) insane++;          // |x| >= 2^67 impossible for bf16 pos in [0,10]
    }
    flags[0] = (insane >= 2) ? 1 : 0;
    int nz = 0;
    for (int i = 1; i < 16; i += 2) nz += (eidx_i32[i] != 0);
    flags[1] = (nz == 0) ? 1 : 0;       // int64 high words all zero
  }
}

// ---------------- Counting sort by dst: zero-cnt, hist, scan, scatter ----------------
__global__ __launch_bounds__(256) void k_zero_cnt(int* __restrict__ cnt) {
  int i = blockIdx.x * 256 + threadIdx.x;
  if (i < NN) cnt[i] = 0;
}

__global__ __launch_bounds__(256) void k_hist(const int* __restrict__ eidx,
                                              int* __restrict__ cnt,
                                              const int* __restrict__ flags) {
  const int i64 = flags[1];
  long e = (long)blockIdx.x * 256 + threadIdx.x;
  if (e < NE) {
    int d = ldidx(eidx, NE + e, i64);
    atomicAdd(&cnt[d], 1);
  }
}

// single block, 1024 threads: exclusive prefix sum of cnt -> cursor
__global__ __launch_bounds__(1024) void k_scan(const int* __restrict__ cnt,
                                               int* __restrict__ cursor) {
  __shared__ int part[1024];
  int t = threadIdx.x;
  const int CH = (NN + 1023) / 1024;   // 49
  int lo = t * CH, hi = lo + CH; if (hi > NN) hi = NN;
  int s = 0;
  for (int i = lo; i < hi; ++i) s += cnt[i];
  part[t] = s;
  __syncthreads();
  for (int off = 1; off < 1024; off <<= 1) {
    int v = (t >= off) ? part[t - off] : 0;
    __syncthreads();
    part[t] += v;
    __syncthreads();
  }
  int run = (t > 0) ? part[t - 1] : 0;
  for (int i = lo; i < hi; ++i) { int c = cnt[i]; cursor[i] = run; run += c; }
}

__global__ __launch_bounds__(256) void k_scatter(const int* __restrict__ eidx,
                                                 int* __restrict__ cursor,
                                                 unsigned long long* __restrict__ sedge,
                                                 const int* __restrict__ flags) {
  const int i64 = flags[1];
  long e = (long)blockIdx.x * 256 + threadIdx.x;
  if (e < NE) {
    int s = ldidx(eidx, e, i64);
    int d = ldidx(eidx, NE + e, i64);
    int p = atomicAdd(&cursor[d], 1);
    sedge[p] = ((unsigned long long)(unsigned)d << 32) | (unsigned)s;
  }
}

// ---------------- Kernel 1: si1 = irreps_linear(nodes) -> bf16 ----------------
__global__ __launch_bounds__(256) void k_linear1(
    const void* __restrict__ nodes,
    const void* __restrict__ W0,
    const void* __restrict__ W1,
    const void* __restrict__ W2,
    unsigned short* __restrict__ si1,
    const int* __restrict__ flags) {
  const int f32 = flags[0];
  __shared__ float Ws[3072];
  __shared__ float xs[NPB * DIMX];
  int tid = threadIdx.x;
  for (int idx = tid; idx < 3072; idx += 256) {
    int l = idx >> 10, rem = idx & 1023;
    const void* w = (l == 0) ? W0 : ((l == 1) ? W1 : W2);
    Ws[idx] = ldf(w, rem, f32);
  }
  long base = (long)blockIdx.x * NPB;
  for (int idx = tid; idx < NPB * DIMX; idx += 256)
    xs[idx] = ldf(nodes, base * DIMX + idx, f32);
  __syncthreads();
  int wid = tid >> 6, lane = tid & 63;
  #pragma unroll 1
  for (int t = 0; t < 4; ++t) {
    int nl = wid * 4 + t;
    long node = base + nl;
    const float* x = xs + nl * DIMX;
    #pragma unroll
    for (int r = 0; r < 5; ++r) {
      int j = r * 64 + lane;
      if (j < DIMX) {
        float acc = 0.f;
        if (j < 32) {
          #pragma unroll
          for (int i = 0; i < 32; ++i) acc += x[i] * Ws[i * 32 + j];
        } else if (j < 128) {
          unsigned jj = j - 32; int m = jj / 3u, c = jj % 3u;
          #pragma unroll
          for (int i = 0; i < 32; ++i) acc += x[32 + 3 * i + c] * Ws[1024 + i * 32 + m];
        } else {
          unsigned jj = j - 128; int m = jj / 5u, c = jj % 5u;
          #pragma unroll
          for (int i = 0; i < 32; ++i) acc += x[128 + 5 * i + c] * Ws[2048 + i * 32 + m];
        }
        si1[node * DIMX + j] = f2b(acc);
      }
    }
  }
}

// ---------------- Kernel 2: zero the conv accumulator ----------------
__global__ __launch_bounds__(256) void k_zero(float* __restrict__ conv) {
  long idx = (long)blockIdx.x * 256 + threadIdx.x;
  if (idx < (long)NN * DIMX / 4) {
    float4 z; z.x = 0.f; z.y = 0.f; z.z = 0.f; z.w = 0.f;
    ((float4*)conv)[idx] = z;
  }
}

// ---------------- Kernel 3: fused edge kernel (dst-sorted edges) ----------------
// Phase A: stage Wr2^T in bufA; geometry (Y->geomY, rbf->bufB); h -> A-frags;
// 28 MFMA. Barrier. Phase B: bufA reused as per-wave bf16 row cache; per
// 4-edge group: unload w once into wall (bufB, overlaid on dead wr1s/rbf),
// ONE fence pair, then a branch-free bulk computing all 4 edges' 20 values
// into registers (deep LDS-read ILP), then the serial run-accumulate/flush.
__global__ __launch_bounds__(256) void k_edges(
    const void* __restrict__ pos,
    const unsigned long long* __restrict__ sedge,
    const void* __restrict__ Wr1,
    const void* __restrict__ br1,
    const void* __restrict__ Wr2,
    const unsigned short* __restrict__ si1,
    float* __restrict__ conv,
    const int* __restrict__ flags) {
  const int f32 = flags[0];
  // bufA: phase A = wr2t[j*72+k] (16128 shorts); phase B = row cache [64][288]
  __shared__ unsigned short bufA[18432];
  // bufB: phase A = wr1s[512]+br1[64] @0, rbf[64][8] @576; phase B = wall[4][4][228]
  __shared__ float bufB[3648];
  __shared__ float geomY[64][8];        // Y1(3) Y2(5), live whole kernel
  __shared__ unsigned int sdv[2][64];   // src, dst
  int tid = threadIdx.x, lane = tid & 63, wid = tid >> 6;

  for (int idx = tid; idx < 512; idx += 256) bufB[idx] = ldf(Wr1, idx, f32);
  if (tid < 64) bufB[512 + tid] = ldf(br1, tid, f32);
  for (int idx = tid; idx < 64 * 224; idx += 256) {   // global-coalesced, transpose into LDS
    int k = idx / 224, j = idx - k * 224;
    bufA[j * 72 + k] = f2b(ldf(Wr2, idx, f32));
  }
  if (tid < 64) {
    long e = (long)blockIdx.x * 64 + tid;
    unsigned long long pr = sedge[e];
    int s = (int)(pr & 0xffffffffu);
    int d = (int)(pr >> 32);
    sdv[0][tid] = (unsigned)s; sdv[1][tid] = (unsigned)d;
    float rx = ldf(pos, 3 * (long)s, f32)     - ldf(pos, 3 * (long)d, f32);
    float ry = ldf(pos, 3 * (long)s + 1, f32) - ldf(pos, 3 * (long)d + 1, f32);
    float rz = ldf(pos, 3 * (long)s + 2, f32) - ldf(pos, 3 * (long)d + 2, f32);
    float dd = sqrtf(rx * rx + ry * ry + rz * rz + 1e-12f);
    float inv = 1.0f / dd;
    float ux = rx * inv, uy = ry * inv, uz = rz * inv;
    geomY[tid][0] = ux; geomY[tid][1] = uy; geomY[tid][2] = uz;
    geomY[tid][3] = ux * uy;
    geomY[tid][4] = uy * uz;
    geomY[tid][5] = (3.f * uz * uz - 1.f) * 0.28867513459481287f;
    geomY[tid][6] = ux * uz;
    geomY[tid][7] = (ux * ux - uy * uy) * 0.5f;
    #pragma unroll
    for (int k = 0; k < 8; ++k) {
      float t = dd - (float)k * (5.0f / 7.0f);
      bufB[576 + tid * 8 + k] = __expf(-t * t);   // rbf
    }
  }
  __syncthreads();

  const int q = lane >> 4, colA = lane & 15;
  const int myrow0 = wid * 16;

  // --- h (scaled by 0.25 = 1/sqrt(AVG_DEG)) into A-fragments ---
  short8 afrag0, afrag1;
  {
    const float* rb = &bufB[576 + (myrow0 + colA) * 8];
    #pragma unroll
    for (int i = 0; i < 8; ++i) {
      int k = q * 8 + i;
      float a = bufB[512 + k];
      #pragma unroll
      for (int r = 0; r < 8; ++r) a += rb[r] * bufB[r * 64 + k];
      afrag0[i] = (short)f2b(0.25f * a / (1.f + __expf(-a)));
      int k2 = 32 + q * 8 + i;
      float a2 = bufB[512 + k2];
      #pragma unroll
      for (int r = 0; r < 8; ++r) a2 += rb[r] * bufB[r * 64 + k2];
      afrag1[i] = (short)f2b(0.25f * a2 / (1.f + __expf(-a2)));
    }
  }

  // --- 28 MFMA: w for all 16 edges of this wave ---
  float4v acc[14];
  #pragma unroll
  for (int t = 0; t < 14; ++t) {
    int j = t * 16 + colA;
    short8 b0 = *(const short8*)&bufA[j * 72 + q * 8];
    short8 b1 = *(const short8*)&bufA[j * 72 + 32 + q * 8];
    float4v c = {0.f, 0.f, 0.f, 0.f};
    c = __builtin_amdgcn_mfma_f32_16x16x32_bf16(afrag0, b0, c, 0, 0, 0);
    c = __builtin_amdgcn_mfma_f32_16x16x32_bf16(afrag1, b1, c, 0, 0, 0);
    acc[t] = c;
  }

  __syncthreads();   // wr2t + wr1s/rbf dead; bufA -> row cache, bufB -> wall

  // --- batch-gather this wave's 16 source rows (bf16, raw copy, b128 I/O) ---
  if (lane < 36) {
    #pragma unroll
    for (int b = 0; b < 2; ++b) {
      uint4 t[8];
      #pragma unroll
      for (int e = 0; e < 8; ++e) {
        unsigned s = sdv[0][myrow0 + b * 8 + e];
        t[e] = ((const uint4*)(si1 + (size_t)s * DIMX))[lane];
      }
      #pragma unroll
      for (int e = 0; e < 8; ++e) {
        ((uint4*)&bufA[(size_t)(myrow0 + b * 8 + e) * 288])[lane] = t[e];
      }
    }
  }

  // --- per-lane output accumulators for the current dst run ---
  float accv[5] = {0.f, 0.f, 0.f, 0.f, 0.f};
  unsigned cur_d = sdv[1][myrow0];
  float* wallw = bufB + wid * 912;      // [4 edges][228]

  #pragma unroll 1
  for (int g = 0; g < 4; ++g) {
    // unload w for this 4-edge group (one fence pair per group, not per edge)
    asm volatile("" ::: "memory");
    if (q == g) {
      #pragma unroll
      for (int reg = 0; reg < 4; ++reg) {
        #pragma unroll
        for (int t = 0; t < 14; ++t)
          wallw[reg * 228 + t * 16 + colA] = acc[t][reg];
      }
    }
    asm volatile("" ::: "memory");

    // branch-free bulk: all 4 edges' values into registers (deep LDS ILP)
    float vals[4][5];
    #pragma unroll
    for (int reg = 0; reg < 4; ++reg) {
      const int eb = myrow0 + g * 4 + reg;
      const float* G = geomY[eb];
      float y1x = G[0], y1y = G[1], y1z = G[2];
      float y20 = G[3], y21 = G[4], y22 = G[5], y23 = G[6], y24 = G[7];
      const unsigned short* X = &bufA[(size_t)eb * 288];
      const float* W = wallw + reg * 228;
      #pragma unroll
      for (int r = 0; r < 5; ++r) {
        int j = r * 64 + lane;
        if (j < DIMX) {
          float val;
          if (j < 32) {
            int m = j;
            float d1 = b2f(X[32 + 3 * m]) * y1x + b2f(X[33 + 3 * m]) * y1y + b2f(X[34 + 3 * m]) * y1z;
            float d2 = b2f(X[128 + 5 * m]) * y20 + b2f(X[129 + 5 * m]) * y21 + b2f(X[130 + 5 * m]) * y22
                     + b2f(X[131 + 5 * m]) * y23 + b2f(X[132 + 5 * m]) * y24;
            val = W[m] * b2f(X[m]) + W[128 + m] * d1 + W[192 + m] * d2;
          } else if (j < 128) {
            unsigned jj = j - 32; int m = jj / 3u, c = jj % 3u;
            float Yc = (c == 0) ? y1x : ((c == 1) ? y1y : y1z);
            val = W[32 + m] * b2f(X[j]) + W[96 + m] * b2f(X[m]) * Yc;
          } else {
            unsigned jj = j - 128; int m = jj / 5u, c = jj % 5u;
            float Yc = (c == 0) ? y20 : (c == 1) ? y21 : (c == 2) ? y22 : (c == 3) ? y23 : y24;
            val = W[64 + m] * b2f(X[j]) + W[160 + m] * b2f(X[m]) * Yc;
          }
          vals[reg][r] = val;
        }
      }
    }

    // serial run-accumulate / flush on precomputed values
    #pragma unroll
    for (int reg = 0; reg < 4; ++reg) {
      const int eb = myrow0 + g * 4 + reg;
      unsigned dn = sdv[1][eb];
      if (dn != cur_d) {               // wave-uniform: flush the finished run
        float* cv = conv + (size_t)cur_d * DIMX;
        #pragma unroll
        for (int r = 0; r < 5; ++r) {
          int j = r * 64 + lane;
          if (j < DIMX) { atomicAdd(cv + j, accv[r]); accv[r] = 0.f; }
        }
        cur_d = dn;
      }
      #pragma unroll
      for (int r = 0; r < 5; ++r) {
        int j = r * 64 + lane;
        if (j < DIMX) accv[r] += vals[reg][r];
      }
    }
  }
  // final flush for the last run
  {
    float* cv = conv + (size_t)cur_d * DIMX;
    #pragma unroll
    for (int r = 0; r < 5; ++r) {
      int j = r * 64 + lane;
      if (j < DIMX) atomicAdd(cv + j, accv[r]);
    }
  }
}

// ---------------- Kernel 4: si2 = linear(conv); mixed = nodes + si2; gate -> fp32 ----------------
__global__ __launch_bounds__(256) void k_gate(
    const float* __restrict__ conv,
    const void* __restrict__ nodes,
    const void* __restrict__ W0,
    const void* __restrict__ W1,
    const void* __restrict__ W2,
    const void* __restrict__ Wg,
    float* __restrict__ out,
    const int* __restrict__ flags) {
  const int f32 = flags[0];
  __shared__ float Ws[3072];
  __shared__ float Wgs[2048];
  __shared__ float xs[NPB * DIMX];
  __shared__ float m0s[NPB][33];
  __shared__ float gs[NPB][65];
  int tid = threadIdx.x;
  for (int idx = tid; idx < 3072; idx += 256) {
    int l = idx >> 10, rem = idx & 1023;
    const void* w = (l == 0) ? W0 : ((l == 1) ? W1 : W2);
    Ws[idx] = ldf(w, rem, f32);
  }
  for (int idx = tid; idx < 2048; idx += 256) Wgs[idx] = ldf(Wg, idx, f32);
  long base = (long)blockIdx.x * NPB;
  for (int idx = tid; idx < NPB * DIMX; idx += 256) xs[idx] = conv[base * DIMX + idx];
  __syncthreads();
  int wid = tid >> 6, lane = tid & 63;
  #pragma unroll 1
  for (int t = 0; t < 4; ++t) {
    int nl = wid * 4 + t;
    long node = base + nl;
    const float* x = xs + nl * DIMX;
    float mixed[5];
    #pragma unroll
    for (int r = 0; r < 5; ++r) {
      int j = r * 64 + lane;
      if (j < DIMX) {
        float acc = 0.f;
        if (j < 32) {
          #pragma unroll
          for (int i = 0; i < 32; ++i) acc += x[i] * Ws[i * 32 + j];
        } else if (j < 128) {
          unsigned jj = j - 32; int m = jj / 3u, c = jj % 3u;
          #pragma unroll
          for (int i = 0; i < 32; ++i) acc += x[32 + 3 * i + c] * Ws[1024 + i * 32 + m];
        } else {
          unsigned jj = j - 128; int m = jj / 5u, c = jj % 5u;
          #pragma unroll
          for (int i = 0; i < 32; ++i) acc += x[128 + 5 * i + c] * Ws[2048 + i * 32 + m];
        }
        acc += ldf(nodes, node * DIMX + j, f32);
        mixed[r] = acc;
        if (j < 32) m0s[nl][j] = acc;
      }
    }
    asm volatile("" ::: "memory");
    {
      float ga = 0.f;
      #pragma unroll
      for (int m = 0; m < 32; ++m) ga += m0s[nl][m] * Wgs[m * 64 + lane];
      gs[nl][lane] = 1.f / (1.f + __expf(-ga));
    }
    asm volatile("" ::: "memory");
    #pragma unroll
    for (int r = 0; r < 5; ++r) {
      int j = r * 64 + lane;
      if (j < DIMX) {
        float v = mixed[r];
        float o;
        if (j < 32) {
          o = v / (1.f + __expf(-v));
        } else if (j < 128) {
          int m = (unsigned)(j - 32) / 3u; o = v * gs[nl][m];
        } else {
          int m = (unsigned)(j - 128) / 5u; o = v * gs[nl][32 + m];
        }
        out[node * DIMX + j] = o;
      }
    }
  }
}

extern "C" void kernel_launch(void* const* d_in, const int* in_sizes, int n_in,
                              void* d_out, int out_size, void* d_ws, size_t ws_size,
                              hipStream_t stream) {
  const void* nodes = d_in[0];
  const void* pos   = d_in[1];
  const void* W0    = d_in[2];
  const void* W1    = d_in[3];
  const void* W2    = d_in[4];
  const void* Wr1   = d_in[5];
  const void* br1   = d_in[6];
  const void* Wr2   = d_in[7];
  const void* Wg    = d_in[8];
  const int* eidx   = (const int*)d_in[10];

  // workspace layout
  int* flags = (int*)d_ws;
  unsigned short* si1 = (unsigned short*)((char*)d_ws + 256);
  size_t conv_off = 256 + (size_t)NN * DIMX * 2;                 // 28,800,256
  float* conv = (float*)((char*)d_ws + conv_off);
  size_t cnt_off = conv_off + (size_t)NN * DIMX * 4;             // 86,400,256
  int* cnt    = (int*)((char*)d_ws + cnt_off);
  int* cursor = (int*)((char*)d_ws + cnt_off + (size_t)NN * 4);  // 86,600,256
  unsigned long long* sedge =
      (unsigned long long*)((char*)d_ws + cnt_off + 2 * (size_t)NN * 4);  // 86,800,256
  float* out = (float*)d_out;

  hipLaunchKernelGGL(k_detect, dim3(1), dim3(64), 0, stream,
                     (const unsigned short*)pos, eidx, flags);
  // counting sort of edges by dst
  hipLaunchKernelGGL(k_zero_cnt, dim3((NN + 255) / 256), dim3(256), 0, stream, cnt);
  hipLaunchKernelGGL(k_hist, dim3((NE + 255) / 256), dim3(256), 0, stream, eidx, cnt, flags);
  hipLaunchKernelGGL(k_scan, dim3(1), dim3(1024), 0, stream, cnt, cursor);
  hipLaunchKernelGGL(k_scatter, dim3((NE + 255) / 256), dim3(256), 0, stream,
                     eidx, cursor, sedge, flags);
  // node pipeline
  hipLaunchKernelGGL(k_linear1, dim3(NN / NPB), dim3(256), 0, stream,
                     nodes, W0, W1, W2, si1, flags);
  hipLaunchKernelGGL(k_zero, dim3((NN * DIMX / 4 + 255) / 256), dim3(256), 0, stream, conv);
  hipLaunchKernelGGL(k_edges, dim3(NE / 64), dim3(256), 0, stream,
                     pos, sedge, Wr1, br1, Wr2, si1, conv, flags);
  hipLaunchKernelGGL(k_gate, dim3(NN / NPB), dim3(256), 0, stream,
                     conv, nodes, W0, W1, W2, Wg, out, flags);
}